// Round 3
// baseline (68.776 us; speedup 1.0000x reference)
//
#include <hip/hip_runtime.h>
#include <stdint.h>

// NeRF "mark untrained cells": out[cas][m] = visible(cas, morton_decode(m)) ? density[cas][m] : -1
// - in_aabb provably always true (|cxyz| <= 3.96875 < 4+h) -> untrained == !visible.
// - Morton scatter inverted: thread per OUTPUT index m -> coalesced loads/stores.
// - fp semantics matched to the reference pair (np einsum + jax dot_general):
//   * cxyz = world*(bnd-h) rounded per cascade BEFORE the dot (reference order)
//   * 3-term dots as FMA CHAINS, j ascending: fma(c2,R2, fma(c1,R1, c0*R0))
//     (np's sum-of-products loop contracts under default -ffp-contract; XLA GEMM = fma chain)
//   * cam = dot(c,R) - dot(t,R): separate ops, each separately rounded (no contraction)
//   * mask rhs = (ax*cz) + T: two separate ufuncs -> unfused __fmul_rn/__fadd_rn
// - R staged in LDS with STRIDED loop (288 > 256 threads; round-1 bug was a plain guard).

constexpr int GRIDN  = 128;
constexpr int NCELLS = GRIDN * GRIDN * GRIDN;   // 2097152
constexpr int NCAMS  = 32;

__device__ __forceinline__ uint32_t compact1by2(uint32_t x) {
    // inverse of reference _part1by2 (valid for 21-bit morton codes)
    x &= 0x09249249u;
    x = (x ^ (x >> 2))  & 0x030c30c3u;
    x = (x ^ (x >> 4))  & 0x0300f00fu;
    x = (x ^ (x >> 8))  & 0x030000ffu;
    x = (x ^ (x >> 16)) & 0x000003ffu;
    return x;
}

__launch_bounds__(256)
__global__ void nerf_mark_kernel(const float* __restrict__ dg,
                                 const float* __restrict__ poses,
                                 const float* __restrict__ intr,
                                 float* __restrict__ out) {
    __shared__ float sR[NCAMS * 9];   // R[b][j][k] = poses[b, j, k]
    __shared__ float sd[NCAMS * 3];   // (t . R)[b][k], fma-chain rounding
    __shared__ float sw[GRIDN];       // world coord table: 2*i/127 - 1
    __shared__ float sax[2];          // cx/fx, cy/fy

    const int tid = threadIdx.x;
    for (int i = tid; i < NCAMS * 9; i += 256) {   // 288 elems, 256 threads
        int b = i / 9, r = i - b * 9;
        int j = r / 3, k = r - j * 3;
        sR[i] = poses[b * 16 + j * 4 + k];
    }
    if (tid < NCAMS * 3) {
        int b = tid / 3, k = tid - b * 3;
        const float* P = poses + b * 16;
        // (t.R)[k] = fma(t2, R2k, fma(t1, R1k, t0*R0k)); t_j = P[j*4+3]
        sd[tid] = fmaf(P[11], P[8 + k], fmaf(P[7], P[4 + k], P[3] * P[k]));
    }
    if (tid < GRIDN) sw[tid] = (2.0f * (float)tid) / 127.0f - 1.0f;
    if (tid == 0) { sax[0] = intr[2] / intr[0]; sax[1] = intr[3] / intr[1]; }
    __syncthreads();

    const int m = blockIdx.x * 256 + tid;
    const uint32_t um = (uint32_t)m;
    const float wx = sw[compact1by2(um)];
    const float wy = sw[compact1by2(um >> 1)];
    const float wz = sw[compact1by2(um >> 2)];
    const float ax = sax[0], ay = sax[1];

    // cascade constants: S = bnd - h (exact in f32), T = 2h (exact)
    constexpr float S0 = 1.0f - 1.0f / 128.0f, T0 = 2.0f / 128.0f;
    constexpr float S1 = 2.0f - 2.0f / 128.0f, T1 = 4.0f / 128.0f;
    constexpr float S2 = 4.0f - 4.0f / 128.0f, T2 = 8.0f / 128.0f;

    // cxyz = world * S, rounded per cascade (reference rounds before the dot)
    const float c0x = __fmul_rn(wx, S0), c0y = __fmul_rn(wy, S0), c0z = __fmul_rn(wz, S0);
    const float c1x = __fmul_rn(wx, S1), c1y = __fmul_rn(wy, S1), c1z = __fmul_rn(wz, S1);
    const float c2x = __fmul_rn(wx, S2), c2y = __fmul_rn(wy, S2), c2z = __fmul_rn(wz, S2);

    bool v0 = false, v1 = false, v2 = false;
    for (int b = 0; b < NCAMS; ++b) {
        const float* R = &sR[b * 9];
        const float R0 = R[0], R1 = R[1], R2 = R[2];
        const float R3 = R[3], R4 = R[4], R5 = R[5];
        const float R6 = R[6], R7 = R[7], R8 = R[8];
        const float dx = sd[b * 3], dy = sd[b * 3 + 1], dz = sd[b * 3 + 2];

        // test(cascade): cam_k = fma(cj2,R2k, fma(cj1,R1k, cj0*R0k)) - d_k (sub unfused)
        auto test = [&](float cjx, float cjy, float cjz, float T) -> bool {
            float px = __fsub_rn(fmaf(cjz, R6, fmaf(cjy, R3, cjx * R0)), dx);
            float py = __fsub_rn(fmaf(cjz, R7, fmaf(cjy, R4, cjx * R1)), dy);
            float pz = __fsub_rn(fmaf(cjz, R8, fmaf(cjy, R5, cjx * R2)), dz);
            bool mz = pz > 0.0f;
            bool mx = fabsf(px) < __fadd_rn(__fmul_rn(ax, pz), T);
            bool my = fabsf(py) < __fadd_rn(__fmul_rn(ay, pz), T);
            return mz & mx & my;
        };

        v0 = v0 | test(c0x, c0y, c0z, T0);
        v1 = v1 | test(c1x, c1y, c1z, T1);
        v2 = v2 | test(c2x, c2y, c2z, T2);

        // wave-uniform early exit: booleans already final for exited lanes
        if (__all(v0 && v1 && v2)) break;
    }

    out[m]              = v0 ? dg[m]              : -1.0f;
    out[NCELLS + m]     = v1 ? dg[NCELLS + m]     : -1.0f;
    out[2 * NCELLS + m] = v2 ? dg[2 * NCELLS + m] : -1.0f;
}

extern "C" void kernel_launch(void* const* d_in, const int* in_sizes, int n_in,
                              void* d_out, int out_size, void* d_ws, size_t ws_size,
                              hipStream_t stream) {
    const float* dg    = (const float*)d_in[0];   // (3, 128^3) f32
    const float* poses = (const float*)d_in[1];   // (32, 4, 4) f32
    const float* intr  = (const float*)d_in[2];   // (4,) f32
    float* out = (float*)d_out;                   // (3, 128^3) f32

    nerf_mark_kernel<<<NCELLS / 256, 256, 0, stream>>>(dg, poses, intr, out);
}